// Round 1
// baseline (630.965 us; speedup 1.0000x reference)
//
#include <hip/hip_runtime.h>
#include <cmath>

#define S 512
#define B 256
#define IN 64
#define H 256

// One workgroup per batch row (256 WGs ~ 1/CU). 512 threads: tid = half*256 + j.
// Thread (j,half) keeps Wh[j, half*128 .. +128) and Wx[j, half*32 .. +32) in
// registers; h, x_t, and partial sums live in LDS. Two barriers per timestep.
__global__ __launch_bounds__(512, 2) void rnn_fused(
    const float* __restrict__ x,   // [S,B,IN]
    const float* __restrict__ Wx,  // [H,IN]
    const float* __restrict__ bx,  // [H]
    const float* __restrict__ Wh,  // [H,H]
    const float* __restrict__ bh,  // [H]
    float* __restrict__ out)       // [S,B,H] ++ [1,B,H]
{
    __shared__ float h_lds[H];
    __shared__ float x_lds[IN];
    __shared__ float part[H];

    const int tid  = threadIdx.x;
    const int j    = tid & (H - 1);
    const int half = tid >> 8;          // 0 or 1 (wave-uniform: waves are 64-aligned)
    const int b    = blockIdx.x;

    // ---- load weights into registers (one-time) ----
    float4 wh4[32];
    {
        const float4* whp = (const float4*)(Wh + (size_t)j * H + half * 128);
        #pragma unroll
        for (int q = 0; q < 32; ++q) wh4[q] = whp[q];
    }
    float4 wx4[8];
    {
        const float4* wxp = (const float4*)(Wx + (size_t)j * IN + half * 32);
        #pragma unroll
        for (int q = 0; q < 8; ++q) wx4[q] = wxp[q];
    }
    const float bias = bh[j] + bx[j];

    // ---- init h = 0, stage x(0) ----
    if (tid < H) h_lds[tid] = 0.0f;
    float4 xreg;
    if (tid < 16) xreg = ((const float4*)(x + (size_t)b * IN))[tid];
    __syncthreads();
    if (tid < 16) ((float4*)x_lds)[tid] = xreg;

    const float4* hs4 = (const float4*)h_lds;
    const float4* xs4 = (const float4*)x_lds;

    for (int t = 0; t < S; ++t) {
        __syncthreads();               // x_lds(t), h_lds(t) visible to all

        // prefetch x(t+1) into registers (no LDS touch yet)
        if (tid < 16 && t + 1 < S)
            xreg = ((const float4*)(x + ((size_t)(t + 1) * B + b) * IN))[tid];

        // partial dot: input slice + recurrent slice (4 independent chains)
        float4 acc = make_float4(0.f, 0.f, 0.f, 0.f);
        #pragma unroll
        for (int q = 0; q < 8; ++q) {
            float4 xv = xs4[half * 8 + q];    // broadcast read
            acc.x += wx4[q].x * xv.x;
            acc.y += wx4[q].y * xv.y;
            acc.z += wx4[q].z * xv.z;
            acc.w += wx4[q].w * xv.w;
        }
        #pragma unroll
        for (int q = 0; q < 32; ++q) {
            float4 hv = hs4[half * 32 + q];   // broadcast read
            acc.x += wh4[q].x * hv.x;
            acc.y += wh4[q].y * hv.y;
            acc.z += wh4[q].z * hv.z;
            acc.w += wh4[q].w * hv.w;
        }
        float a = acc.x + acc.y + acc.z + acc.w;

        if (half) part[j] = a;
        __syncthreads();               // partials ready; all reads of h/x(t) done

        if (!half) {
            float pre = a + part[j] + bias;
            pre = fminf(fmaxf(pre, -15.f), 15.f);
            float e  = __expf(2.f * pre);
            float hv = (e - 1.f) / (e + 1.f);   // tanh
            h_lds[j] = hv;
            out[((size_t)t * B + b) * H + j] = hv;
            if (tid < 16) ((float4*)x_lds)[tid] = xreg;   // stage x(t+1)
        }
    }

    // h_last = h_seq[S-1]; each tid<H reads the h_lds slot it just wrote
    if (tid < H)
        out[(size_t)S * B * H + (size_t)b * H + tid] = h_lds[tid];
}

extern "C" void kernel_launch(void* const* d_in, const int* in_sizes, int n_in,
                              void* d_out, int out_size, void* d_ws, size_t ws_size,
                              hipStream_t stream) {
    const float* x  = (const float*)d_in[0];
    const float* Wx = (const float*)d_in[1];
    const float* bx = (const float*)d_in[2];
    const float* Wh = (const float*)d_in[3];
    const float* bh = (const float*)d_in[4];
    float* out = (float*)d_out;

    rnn_fused<<<dim3(B), dim3(512), 0, stream>>>(x, Wx, bx, Wh, bh, out);
}

// Round 2
// 577.193 us; speedup vs baseline: 1.0932x; 1.0932x over previous
//
#include <hip/hip_runtime.h>
#include <cmath>

#define S 512
#define B 256
#define IN 64
#define H 256
#define NS 16      // k-slices (s = tid>>5)
#define KH 16      // h elems per slice
#define KX 4       // x elems per slice
#define R 8        // outputs per thread, j = jg + 32*r
#define HPAD 20    // h_buf row stride per 16 elems (bank spread, 16B aligned)
#define PPAD 18    // part row stride (b64-aligned, <=2-way banks on write)

// 256 blocks (one batch row each) x 512 threads (8 waves).
// Thread (jg = tid&31, s = tid>>5) computes partial dots for 8 outputs
// j = jg+32r over k-slice [s*16, s*16+16) of h and [s*4, s*4+4) of x.
// Weights pinned in VGPRs via runtime `scale` (load*scale is not
// rematerializable -> must stay live). K-split reduced via LDS partials.
__global__ __launch_bounds__(512, 2) void rnn_fused2(
    const float* __restrict__ x,   // [S,B,IN]
    const float* __restrict__ Wx,  // [H,IN]
    const float* __restrict__ bx,  // [H]
    const float* __restrict__ Wh,  // [H,H]
    const float* __restrict__ bh,  // [H]
    float* __restrict__ out,       // [S,B,H] ++ [1,B,H]
    float scale)                   // 1.0f at runtime
{
    __shared__ float h_buf[16 * HPAD];   // h[k] at (k>>4)*HPAD + (k&15)
    __shared__ float x_buf[IN];
    __shared__ float part[H * PPAD];     // part[j][s]

    const int tid = threadIdx.x;
    const int jg  = tid & 31;
    const int s   = tid >> 5;
    const int b   = blockIdx.x;

    // ---- load + pin weights ----
    float4 wh[R][KH / 4];
    float4 wx[R];
    #pragma unroll
    for (int r = 0; r < R; ++r) {
        const int j = jg + 32 * r;
        const float4* whp = (const float4*)(Wh + (size_t)j * H + s * KH);
        #pragma unroll
        for (int q = 0; q < KH / 4; ++q) {
            float4 v = whp[q];
            wh[r][q] = make_float4(v.x * scale, v.y * scale, v.z * scale, v.w * scale);
        }
        float4 u = *(const float4*)(Wx + (size_t)j * IN + s * KX);
        wx[r] = make_float4(u.x * scale, u.y * scale, u.z * scale, u.w * scale);
    }

    float bias = 0.f, last_h = 0.f;
    if (tid < H) bias = bh[tid] + bx[tid];

    // ---- init h = 0, stage x(0) ----
    if (tid < 16 * HPAD) h_buf[tid] = 0.f;
    float4 xpre;
    if (tid < 16) {
        xpre = ((const float4*)(x + (size_t)b * IN))[tid];
        ((float4*)x_buf)[tid] = xpre;
    }

    for (int t = 0; t < S; ++t) {
        __syncthreads();               // h_buf/x_buf for step t visible

        // prefetch x(t+1) into registers
        if (tid < 16 && t + 1 < S)
            xpre = ((const float4*)(x + ((size_t)(t + 1) * B + b) * IN))[tid];

        // slice reads: 4+1 b128, <=2 distinct addrs per instr (free)
        const float4* hb = (const float4*)(h_buf + s * HPAD);
        float4 h0 = hb[0], h1 = hb[1], h2 = hb[2], h3 = hb[3];
        float4 xv = *(const float4*)(x_buf + s * KX);

        float acc[R];
        #pragma unroll
        for (int r = 0; r < R; ++r) acc[r] = 0.f;

        #pragma unroll
        for (int q = 0; q < 4; ++q) {
            float4 hq = (q == 0) ? h0 : (q == 1) ? h1 : (q == 2) ? h2 : h3;
            #pragma unroll
            for (int r = 0; r < R; ++r) {   // 8 independent chains
                acc[r] += wh[r][q].x * hq.x;
                acc[r] += wh[r][q].y * hq.y;
                acc[r] += wh[r][q].z * hq.z;
                acc[r] += wh[r][q].w * hq.w;
            }
        }
        #pragma unroll
        for (int r = 0; r < R; ++r) {
            acc[r] += wx[r].x * xv.x;
            acc[r] += wx[r].y * xv.y;
            acc[r] += wx[r].z * xv.z;
            acc[r] += wx[r].w * xv.w;
        }

        // scatter partials: 8 b32, bank = (18*(jg+32r)+s)%32 -> <=2-way
        #pragma unroll
        for (int r = 0; r < R; ++r)
            part[(jg + 32 * r) * PPAD + s] = acc[r];

        __syncthreads();               // partials visible; slice reads done

        if (tid < H) {
            const float2* pp = (const float2*)(part + tid * PPAD);
            float2 a0 = pp[0], a1 = pp[1], a2 = pp[2], a3 = pp[3];
            float2 a4 = pp[4], a5 = pp[5], a6 = pp[6], a7 = pp[7];
            float sum = ((a0.x + a0.y) + (a1.x + a1.y))
                      + ((a2.x + a2.y) + (a3.x + a3.y))
                      + ((a4.x + a4.y) + (a5.x + a5.y))
                      + ((a6.x + a6.y) + (a7.x + a7.y));
            float pre = sum + bias;
            pre = fminf(fmaxf(pre, -15.f), 15.f);
            float e  = __expf(2.f * pre);
            float hv = (e - 1.f) / (e + 1.f);
            last_h = hv;
            h_buf[((tid >> 4) * HPAD) + (tid & 15)] = hv;
            out[((size_t)t * B + b) * H + tid] = hv;     // coalesced
        }
        if (tid < 16) ((float4*)x_buf)[tid] = xpre;      // stage x(t+1)
    }

    if (tid < H)
        out[(size_t)S * B * H + (size_t)b * H + tid] = last_h;
}

extern "C" void kernel_launch(void* const* d_in, const int* in_sizes, int n_in,
                              void* d_out, int out_size, void* d_ws, size_t ws_size,
                              hipStream_t stream) {
    const float* x  = (const float*)d_in[0];
    const float* Wx = (const float*)d_in[1];
    const float* bx = (const float*)d_in[2];
    const float* Wh = (const float*)d_in[3];
    const float* bh = (const float*)d_in[4];
    float* out = (float*)d_out;

    rnn_fused2<<<dim3(B), dim3(512), 0, stream>>>(x, Wx, bx, Wh, bh, out, 1.0f);
}

// Round 3
// 566.876 us; speedup vs baseline: 1.1131x; 1.0182x over previous
//
#include <hip/hip_runtime.h>
#include <cmath>

#define S 512
#define B 256
#define IN 64
#define H 256
#define NS 16      // k-slices (s = tid>>5)
#define KH 16      // h elems per slice
#define KX 4       // x elems per slice
#define R 8        // outputs per thread, j = jg + 32*r
#define HPAD 20    // h_buf row stride per 16 elems (16B aligned, broadcast reads)
#define PPAD 17    // part stride: gcd(17,32)=1 -> conflict-free b32 writes/reads

// 256 blocks (one batch row each) x 512 threads (8 waves, 2/SIMD).
// Thread (jg = tid&31, s = tid>>5) computes partial dots for 8 outputs
// j = jg+32r over k-slice [s*16,+16) of h and [s*4,+4) of x.
// Weights are pinned in VGPRs with an opaque empty-asm "+v" constraint:
// an asm def cannot be rematerialized, so the 160 floats stay live.
__global__ __launch_bounds__(512, 2) void rnn_fused3(
    const float* __restrict__ x,   // [S,B,IN]
    const float* __restrict__ Wx,  // [H,IN]
    const float* __restrict__ bx,  // [H]
    const float* __restrict__ Wh,  // [H,H]
    const float* __restrict__ bh,  // [H]
    float* __restrict__ out)       // [S,B,H] ++ [1,B,H]
{
    __shared__ float h_buf[16 * HPAD];   // h[k] at (k>>4)*HPAD + (k&15)
    __shared__ float x_buf[IN];
    __shared__ float part[H * PPAD];     // part[j*17 + s]

    const int tid = threadIdx.x;
    const int jg  = tid & 31;
    const int s   = tid >> 5;
    const int b   = blockIdx.x;

    // ---- one-time weight load ----
    float4 wh[R][KH / 4];
    float4 wx[R];
    #pragma unroll
    for (int r = 0; r < R; ++r) {
        const int j = jg + 32 * r;
        const float4* whp = (const float4*)(Wh + (size_t)j * H + s * KH);
        #pragma unroll
        for (int q = 0; q < KH / 4; ++q) wh[r][q] = whp[q];
        wx[r] = *(const float4*)(Wx + (size_t)j * IN + s * KX);
    }
    // ---- pin in VGPRs: opaque defs, not rematerializable ----
    #pragma unroll
    for (int r = 0; r < R; ++r) {
        #pragma unroll
        for (int q = 0; q < KH / 4; ++q)
            asm volatile("" : "+v"(wh[r][q].x), "+v"(wh[r][q].y),
                              "+v"(wh[r][q].z), "+v"(wh[r][q].w));
        asm volatile("" : "+v"(wx[r].x), "+v"(wx[r].y),
                          "+v"(wx[r].z), "+v"(wx[r].w));
    }

    float bias = 0.f, last_h = 0.f;
    if (tid < H) bias = bh[tid] + bx[tid];

    // ---- init h = 0, stage x(0) ----
    if (tid < 16 * HPAD) h_buf[tid] = 0.f;
    float4 xpre;
    const float4* xsrc = (const float4*)(x + (size_t)b * IN) + (tid & 15);
    if (tid < 16) {
        xpre = *xsrc;
        ((float4*)x_buf)[tid] = xpre;
        xsrc += (B * IN) / 4;          // advance to t=1
    }

    float* outp = out + (size_t)b * H + tid;   // valid for tid<H
    const float4* hb = (const float4*)(h_buf + s * HPAD);
    const float4* xs = (const float4*)(x_buf + s * KX);

    for (int t = 0; t < S; ++t) {
        __syncthreads();               // h_buf/x_buf for step t visible

        // prefetch x(t+1) into registers (pointer-increment addressing)
        if (tid < 16 && t + 1 < S) { xpre = *xsrc; xsrc += (B * IN) / 4; }

        // slice reads: 4+1 b128, <=2 distinct addrs per instr (free)
        float4 h0 = hb[0], h1 = hb[1], h2 = hb[2], h3 = hb[3];
        float4 xv = *xs;

        float acc[R];
        #pragma unroll
        for (int r = 0; r < R; ++r) acc[r] = 0.f;

        #pragma unroll
        for (int q = 0; q < 4; ++q) {
            float4 hq = (q == 0) ? h0 : (q == 1) ? h1 : (q == 2) ? h2 : h3;
            #pragma unroll
            for (int r = 0; r < R; ++r) {   // 8 independent chains
                acc[r] += wh[r][q].x * hq.x;
                acc[r] += wh[r][q].y * hq.y;
                acc[r] += wh[r][q].z * hq.z;
                acc[r] += wh[r][q].w * hq.w;
            }
        }
        #pragma unroll
        for (int r = 0; r < R; ++r) {
            acc[r] += wx[r].x * xv.x;
            acc[r] += wx[r].y * xv.y;
            acc[r] += wx[r].z * xv.z;
            acc[r] += wx[r].w * xv.w;
        }

        // scatter partials: banks (17*(jg+32r)+s)%32 -> 2-way max (free)
        #pragma unroll
        for (int r = 0; r < R; ++r)
            part[(jg + 32 * r) * PPAD + s] = acc[r];

        __syncthreads();               // partials visible; slice reads drained

        if (tid < H) {
            const float* pp = part + tid * PPAD;
            float sum = bias;
            #pragma unroll
            for (int q = 0; q < NS; ++q) sum += pp[q];   // 2-way banks (free)
            float pre = fminf(fmaxf(sum, -15.f), 15.f);
            float e  = __expf(2.f * pre);
            float hv = (e - 1.f) / (e + 1.f);
            last_h = hv;
            h_buf[((tid >> 4) * HPAD) + (tid & 15)] = hv;
            *outp = hv;                // coalesced b32
            outp += B * H;
        }
        if (tid < 16) ((float4*)x_buf)[tid] = xpre;      // stage x(t+1)
    }

    if (tid < H)
        out[(size_t)S * B * H + (size_t)b * H + tid] = last_h;
}

extern "C" void kernel_launch(void* const* d_in, const int* in_sizes, int n_in,
                              void* d_out, int out_size, void* d_ws, size_t ws_size,
                              hipStream_t stream) {
    const float* x  = (const float*)d_in[0];
    const float* Wx = (const float*)d_in[1];
    const float* bx = (const float*)d_in[2];
    const float* Wh = (const float*)d_in[3];
    const float* bh = (const float*)d_in[4];
    float* out = (float*)d_out;

    rnn_fused3<<<dim3(B), dim3(512), 0, stream>>>(x, Wx, bx, Wh, bh, out);
}